// Round 9
// baseline (260.151 us; speedup 1.0000x reference)
//
#include <hip/hip_runtime.h>
#include <hip/hip_bf16.h>
#include <cstddef>
#include <cstdint>

#define B_SZ   8
#define T_CTX  1024
#define C_DIM  1024
#define H_NUM  16
#define HS     64
#define M_ROWS (B_SZ * T_CTX)

typedef __attribute__((ext_vector_type(8))) short bf16x8;
typedef __attribute__((ext_vector_type(8))) unsigned short u16x8;
typedef __attribute__((ext_vector_type(4))) float f32x4;

static __device__ inline unsigned short f2bf(float f) {
    __hip_bfloat16 h = __float2bfloat16(f);
    return __builtin_bit_cast(unsigned short, h);
}
static __device__ inline float bf2f(unsigned short u) {
    unsigned int v = ((unsigned int)u) << 16;
    return __builtin_bit_cast(float, v);
}
static __device__ inline void gld16(const void* g, void* l) {
    __builtin_amdgcn_global_load_lds((const __attribute__((address_space(1))) void*)g,
                                     (__attribute__((address_space(3))) void*)l,
                                     16, 0, 0);
}

// ---------------------------------------------------------------------------
// Fused conversion: blocks [0,8192) do x->xs (bf16, time-shifted);
// blocks [8192,12288) do the 4 weight matrices -> stacked bf16.
// ---------------------------------------------------------------------------
__global__ __launch_bounds__(256)
void convert_all(const float* __restrict__ x, unsigned short* __restrict__ xs,
                 const float* __restrict__ Wk, const float* __restrict__ Wv,
                 const float* __restrict__ Wr, const float* __restrict__ Wo,
                 unsigned short* __restrict__ wdst)
{
    const int bid = blockIdx.x;
    if (bid < 8192) {
        const int idx = (bid * 256 + threadIdx.x) * 4;
        const int m = idx >> 10;
        const int c = idx & 1023;
        float4 v;
        if (c < 512) {
            const int t = m & (T_CTX - 1);
            if (t == 0) v = make_float4(0.f, 0.f, 0.f, 0.f);
            else        v = *(const float4*)(x + (size_t)(m - 1) * C_DIM + c);
        } else {
            v = *(const float4*)(x + idx);
        }
        ushort4 o;
        o.x = f2bf(v.x); o.y = f2bf(v.y); o.z = f2bf(v.z); o.w = f2bf(v.w);
        *(ushort4*)(xs + idx) = o;
    } else {
        const int wid = bid - 8192;
        const int z = wid >> 10;
        const float* src = (z == 0) ? Wk : (z == 1) ? Wv : (z == 2) ? Wr : Wo;
        const int idx = ((wid & 1023) * 256 + threadIdx.x) * 4;
        const float4 v = *(const float4*)(src + idx);
        ushort4 o;
        o.x = f2bf(v.x); o.y = f2bf(v.y); o.z = f2bf(v.z); o.w = f2bf(v.w);
        *(ushort4*)(wdst + (size_t)z * (C_DIM * C_DIM) + idx) = o;
    }
}

// ---------------------------------------------------------------------------
// bf16 MFMA GEMM, BK=64, XOR-swizzled LDS (slot = chunk ^ (row&7)).
// FROZEN (r0-r8 proven): __launch_bounds__(256,2), 32 KiB LDS, 2-phase loop.
// r7/r8 epilogue: bf16 modes write via LDS transpose (256B rows), swizzle
// key ((row>>2)&7)<<5 -> conflict-free.  61 us / ~845 TF on the big GEMM.
// multi=1: W stacked [3072x1024]; mode = n0>>10:
//   0: exp(clip)->fp32 expk ; 1: identity->bf16 v ; 2: sigmoid->bf16 sigr
// multi=0: mode 3: (v+bias)*gamma[t] -> fp32 out (64B segments)
// Block swizzle: d -> y=((d&7)<<3)|((d>>3)&7), x=d>>6 (XCD L2 locality).
// ---------------------------------------------------------------------------
__global__ __launch_bounds__(256, 2)
void mfma_gemm64(const unsigned short* __restrict__ A,
                 const unsigned short* __restrict__ Wb,
                 const float* __restrict__ b0, const float* __restrict__ b1,
                 const float* __restrict__ b2,
                 void* __restrict__ o0, void* __restrict__ o1, void* __restrict__ o2,
                 const float* __restrict__ gamma, int multi)
{
    const int d  = blockIdx.x;
    const int y  = ((d & 7) << 3) | ((d >> 3) & 7);
    const int xb = d >> 6;
    const int m0 = y * 128, n0 = xb * 128;

    int mode, ncol0;
    const float* bias;
    void* out;
    if (multi) {
        const int z = n0 >> 10;
        mode = z;
        ncol0 = n0 & 1023;
        bias = (z == 0) ? b0 : (z == 1) ? b1 : b2;
        out  = (z == 0) ? o0 : (z == 1) ? o1 : o2;
    } else {
        mode = 3; ncol0 = n0; bias = b0; out = o0;
    }

    // single 32KB buffer: [0,8192) = A-tile, [8192,16384) = B-tile;
    // whole buffer reused as the bf16 C-staging area in the epilogue.
    __shared__ unsigned short Sh[2 * 128 * 64];

    const int tid = threadIdx.x;
    const int w = tid >> 6, l = tid & 63;

    const int r8  = l >> 3;
    const int c16 = ((l & 7) ^ r8) * 8;
    const unsigned short* gA = A  + (size_t)(m0 + w * 32 + r8) * C_DIM + c16;
    const unsigned short* gB = Wb + (size_t)(n0 + w * 32 + r8) * C_DIM + c16;
    char* lA = (char*)Sh + (w * 32) * 128;
    char* lB = (char*)Sh + 16384 + (w * 32) * 128;

    const int wr = w >> 1, wc = w & 1;
    const int lr = l & 15, lkq = l >> 4;
    const int x7 = lr & 7;

    f32x4 acc[4][4];
    #pragma unroll
    for (int i = 0; i < 4; ++i)
        #pragma unroll
        for (int j = 0; j < 4; ++j) acc[i][j] = (f32x4){0.f, 0.f, 0.f, 0.f};

    for (int k0 = 0; k0 < C_DIM; k0 += 64) {
        #pragma unroll
        for (int r = 0; r < 4; ++r) {
            gld16(gA + k0 + (size_t)r * 8 * C_DIM, lA + r * 8 * 128);
            gld16(gB + k0 + (size_t)r * 8 * C_DIM, lB + r * 8 * 128);
        }
        __syncthreads();

        bf16x8 af[2][4], bfv[2][4];
        #pragma unroll
        for (int ks = 0; ks < 2; ++ks) {
            const int slot = ((ks * 4 + lkq) ^ x7) * 8;   // swizzled k-offset
            #pragma unroll
            for (int i = 0; i < 4; ++i)
                af[ks][i] = *(const bf16x8*)&Sh[(wr * 64 + i * 16 + lr) * 64 + slot];
            #pragma unroll
            for (int j = 0; j < 4; ++j)
                bfv[ks][j] = *(const bf16x8*)&Sh[8192 + (wc * 64 + j * 16 + lr) * 64 + slot];
        }
        #pragma unroll
        for (int ks = 0; ks < 2; ++ks)
            #pragma unroll
            for (int i = 0; i < 4; ++i)
                #pragma unroll
                for (int j = 0; j < 4; ++j)
                    acc[i][j] = __builtin_amdgcn_mfma_f32_16x16x32_bf16(
                        af[ks][i], bfv[ks][j], acc[i][j], 0, 0, 0);
        __syncthreads();
    }

    // epilogue: C/D layout col=lane&15, row=(lane>>4)*4+reg
    if (mode == 1 || mode == 2) {
        // ---- bf16 modes: LDS-transposed coalesced stores ----
        char* const Cs = (char*)Sh;   // 32KB, dead after final K-loop barrier
        #pragma unroll
        for (int j = 0; j < 4; ++j) {
            const int col_l = wc * 64 + j * 16 + lr;
            const float bz = bias[ncol0 + col_l];
            #pragma unroll
            for (int i = 0; i < 4; ++i) {
                const int rbl = wr * 64 + i * 16 + lkq * 4;
                #pragma unroll
                for (int r = 0; r < 4; ++r) {
                    const int row_l = rbl + r;
                    float v = acc[i][j][r] + bz;
                    if (mode == 2) v = 1.f / (1.f + __expf(-v));
                    const int byte = row_l * 256 + ((col_l * 2) ^ (((row_l >> 2) & 7) << 5));
                    *(unsigned short*)(Cs + byte) = f2bf(v);
                }
            }
        }
        __syncthreads();
        // 16 lanes x 16B = 256B contiguous per output row; 8 rounds x 16 rows
        #pragma unroll
        for (int it = 0; it < 8; ++it) {
            const int row_l = (tid >> 4) + it * 16;
            const int k = tid & 15;
            const int byte = row_l * 256 + ((k * 16) ^ (((row_l >> 2) & 7) << 5));
            const u16x8 v = *(const u16x8*)(Cs + byte);
            *(u16x8*)((unsigned short*)out + (size_t)(m0 + row_l) * C_DIM + ncol0 + k * 8) = v;
        }
    } else {
        // ---- fp32 modes (0,3): original path (64B segments, no amplification)
        #pragma unroll
        for (int j = 0; j < 4; ++j) {
            const int col = ncol0 + wc * 64 + j * 16 + lr;
            const float bz = bias[col];
            #pragma unroll
            for (int i = 0; i < 4; ++i) {
                const int rb = m0 + wr * 64 + i * 16 + lkq * 4;
                #pragma unroll
                for (int r = 0; r < 4; ++r) {
                    const int row = rb + r;
                    float v = acc[i][j][r] + bz;
                    if (mode == 0)      v = __expf(fminf(fmaxf(v, -60.f), 30.f));
                    else                v *= gamma[row & (T_CTX - 1)];
                    ((float*)out)[(size_t)row * C_DIM + col] = v;
                }
            }
        }
    }
}

// ---------------------------------------------------------------------------
// Chunk-local cumsum of expk + kvT[b,h,c,u] = bf16(expk * v * alpha[h,u]).
// 64-row chunks (q in [0,16)); static u16x8 indexing (rule #20), 8-deep MLP.
// kvT stores transposed through LDS (r6 win): wave stages [64c][64u] tile
// (stride 68 -> <=4-way aliasing), writes 8x128B contiguous runs.
// sumk holds CHUNK-LOCAL prefix sums; aux[b,q,n] = raw 64-chunk totals.
// ---------------------------------------------------------------------------
__global__ __launch_bounds__(256)
void cumsum_chunk(const float* __restrict__ expk, const unsigned short* __restrict__ vbf,
                  const float* __restrict__ alpha,
                  float* __restrict__ sumk, unsigned short* __restrict__ kvT,
                  float* __restrict__ aux)
{
    __shared__ unsigned short kvs[4][64 * 68];
    const int tid = threadIdx.x;
    const int w = tid >> 6, l = tid & 63;
    const int n = blockIdx.x * 256 + tid;    // channel; c = n&63 = l
    const int q = blockIdx.y;                // 16 chunks of 64 rows
    const int b = blockIdx.z;
    const int h = n >> 6;                    // = blockIdx.x*4 + w (wave-uniform)
    const size_t base = ((size_t)b * T_CTX + q * 64) * C_DIM + n;
    const float* arow = alpha + h * T_CTX + q * 64;

    float s = 0.f;
    for (int g = 0; g < 8; ++g) {
        u16x8 buf;
        #pragma unroll
        for (int k = 0; k < 8; ++k) {
            const int i = g * 8 + k;
            const size_t idx = base + (size_t)i * C_DIM;
            const float e  = expk[idx];
            const float vv = bf2f(vbf[idx]);
            s += e;
            sumk[idx] = s;
            buf[k] = f2bf(e * vv * arow[i]);
        }
        *(u16x8*)&kvs[w][l * 68 + g * 8] = buf;
    }
    aux[((size_t)b * 16 + q) * C_DIM + n] = s;

    __syncthreads();

    // transposed write-out: lane l covers row c2=(l>>3)+r*8, u-slice (l&7)*8.
    const int u8 = (l & 7) * 8;
    #pragma unroll
    for (int r = 0; r < 8; ++r) {
        const int c2 = (l >> 3) + r * 8;
        const u16x8 v = *(const u16x8*)&kvs[w][c2 * 68 + u8];
        *(u16x8*)(kvT + (((size_t)b * H_NUM + h) * HS + c2) * T_CTX + q * 64 + u8) = v;
    }
}

// ---------------------------------------------------------------------------
// wkv via MFMA (Toeplitz):  wkv[t,c] = sum_u twx[1023-t+u] * kvT[c,u]
// r8: load-balanced chunk pairing (bxp, 7-bxp) -> constant 18 steps/block.
// r9 changes:
//  (1) XCD-clustered 1-D grid: the 4 blocks sharing a (b,h) kvT panel get
//      ids with equal id%8 -> same XCD -> 128KB panel L2-resident after
//      first touch (was 4 separate HBM streams, ~4.5x re-read).
//  (2) Double-buffered kv_s: per step {issue next global loads -> MFMA
//      (hides HBM latency) -> ds_write next buf -> ONE __syncthreads}.
//      Was 2 barriers/step with the load-wait exposed.
//  (3) aux prefix offsets for BOTH passes hoisted to kernel start (latency
//      hidden under repl build + pass 1).
// Epilogue staging in dedicated cst (16KB); swizzle key ((row>>2)&3)<<5.
// LDS 55.7KB -> 2 blocks/CU (512 blocks = exactly 2/CU, all co-resident).
// ---------------------------------------------------------------------------
#define REPL_STRIDE 1176
#define REPL_USED   1168

__global__ __launch_bounds__(256)
void wkv_mfma(const unsigned short* __restrict__ kvT,
              const float* __restrict__ sumk,
              const unsigned short* __restrict__ sigr,
              const float* __restrict__ tw, const float* __restrict__ beta,
              const float* __restrict__ aux,
              unsigned short* __restrict__ rwkv)
{
    __shared__ unsigned short repl[8 * REPL_STRIDE];
    __shared__ unsigned short kv_s[2][64 * 72];
    __shared__ unsigned short tw_s[1024];
    __shared__ unsigned short cst[128 * 64];   // epilogue staging (16KB)

    const int tid = threadIdx.x;
    // XCD-clustered decode: id = r + (bxp<<3) + (m<<5); g = r + 8m -> same
    // (b,h) group's 4 blocks share id%8 (round-robin XCD residue).
    const int id  = blockIdx.x;                // 0..511
    const int bxp = (id >> 3) & 3;             // pair selector 0..3
    const int g   = (id & 7) | ((id >> 5) << 3);  // 0..127
    const int h   = g & 15;
    const int b   = g >> 4;

    {
        const int i = tid * 4;
        const float4 v = *(const float4*)(tw + h * T_CTX + i);
        ushort4 o;
        o.x = f2bf(v.x); o.y = f2bf(v.y); o.z = f2bf(v.z); o.w = f2bf(v.w);
        *(ushort4*)&tw_s[i] = o;
    }
    __syncthreads();

    #pragma unroll
    for (int r = 0; r < 8; ++r)
        for (int i = tid; i < REPL_USED; i += 256) {
            const int src = i + r;
            repl[r * REPL_STRIDE + i] = (src < 1024) ? tw_s[src] : (unsigned short)0;
        }

    const int w = tid >> 6, l = tid & 63;
    const int wr = w >> 1, wc = w & 1;
    const int lr = l & 15, lkq = l >> 4;
    const int r    = (7 - lr) & 7;
    const char* repl_c = (const char*)repl;

    const int srow = tid >> 2;
    const int ucol = (tid & 3) * 16;
    const unsigned short* gkv = kvT + (((size_t)b * H_NUM + h) * HS + srow) * T_CTX + ucol;

    // hoisted aux prefix offsets for both passes (chunk index 2*bx + wr)
    float off01[2][2];
    #pragma unroll
    for (int p = 0; p < 2; ++p) {
        const int bx = p ? (7 - bxp) : bxp;
        const int cq = 2 * bx + wr;
        #pragma unroll
        for (int j = 0; j < 2; ++j) {
            const int cl = wc * 32 + j * 16 + lr;
            float o = 0.f;
            for (int q = 0; q < cq; ++q)
                o += aux[((size_t)b * 16 + q) * C_DIM + h * HS + cl];
            off01[p][j] = o;
        }
    }

    for (int pass = 0; pass < 2; ++pass) {
        const int bx = pass ? (7 - bxp) : bxp;
        const int t0 = bx * 128;
        const int S0 = 1023 - t0 - wr * 64 - lr + lkq * 8;
        const int abase = 2 * S0 + (2 * REPL_STRIDE - 2) * r;

        f32x4 acc[4][2];
        #pragma unroll
        for (int i = 0; i < 4; ++i) {
            acc[i][0] = (f32x4){0.f, 0.f, 0.f, 0.f};
            acc[i][1] = (f32x4){0.f, 0.f, 0.f, 0.f};
        }

        const int nsteps = t0 / 64 + 2;

        // prologue: tile 0 into buf 0
        {
            const u16x8 p0 = *(const u16x8*)(gkv);
            const u16x8 p1 = *(const u16x8*)(gkv + 8);
            unsigned short* skv = &kv_s[0][srow * 72 + ucol];
            *(u16x8*)skv       = p0;
            *(u16x8*)(skv + 8) = p1;
        }
        __syncthreads();

        int cur = 0;
        for (int ks = 0; ks < nsteps; ++ks) {
            u16x8 qn0, qn1;
            const bool more = (ks + 1 < nsteps);
            if (more) {
                const int un = (ks + 1) * 64;
                qn0 = *(const u16x8*)(gkv + un);
                qn1 = *(const u16x8*)(gkv + un + 8);
            }

            const unsigned short* kcur = &kv_s[cur][0];
            const int ub = abase + 2 * (ks * 64);
            #pragma unroll
            for (int kk = 0; kk < 2; ++kk) {
                bf16x8 af[4], bfv[2];
                #pragma unroll
                for (int i = 0; i < 4; ++i)
                    af[i] = *(const bf16x8*)(repl_c + (ub + kk * 64 - i * 32));
                #pragma unroll
                for (int j = 0; j < 2; ++j)
                    bfv[j] = *(const bf16x8*)&kcur[(wc * 32 + j * 16 + lr) * 72 + kk * 32 + lkq * 8];
                #pragma unroll
                for (int i = 0; i < 4; ++i)
                    #pragma unroll
                    for (int j = 0; j < 2; ++j)
                        acc[i][j] = __builtin_amdgcn_mfma_f32_16x16x32_bf16(
                            af[i], bfv[j], acc[i][j], 0, 0, 0);
            }

            if (more) {
                unsigned short* skv = &kv_s[cur ^ 1][srow * 72 + ucol];
                *(u16x8*)skv       = qn0;
                *(u16x8*)(skv + 8) = qn1;
            }
            __syncthreads();
            cur ^= 1;
        }

        // ---- epilogue via dedicated cst staging ----
        char* const Cc = (char*)cst;   // 128 rows x 64 ch bf16 = 16KB
        #pragma unroll
        for (int i = 0; i < 4; ++i) {
            const int rbl = wr * 64 + i * 16 + lkq * 4;
            #pragma unroll
            for (int rg = 0; rg < 4; ++rg) {
                const int row_l = rbl + rg;
                const int t = t0 + row_l;
                const float bet = beta[h * T_CTX + t];
                const size_t row_off = ((size_t)(b * T_CTX + t)) * C_DIM + h * HS;
                #pragma unroll
                for (int j = 0; j < 2; ++j) {
                    const int cl = wc * 32 + j * 16 + lr;
                    const float sk = sumk[row_off + cl] + off01[pass][j];
                    const float sr = bf2f(sigr[row_off + cl]);
                    const int byte = row_l * 128 + ((cl * 2) ^ (((row_l >> 2) & 3) << 5));
                    *(unsigned short*)(Cc + byte) = f2bf(sr * bet * acc[i][j][rg] / sk);
                }
            }
        }
        __syncthreads();
        // 8 lanes x 16B = 128B contiguous per row; 4 rounds x 32 rows
        #pragma unroll
        for (int it = 0; it < 4; ++it) {
            const int row_l = (tid >> 3) + it * 32;
            const int k = tid & 7;
            const int byte = row_l * 128 + ((k * 16) ^ (((row_l >> 2) & 3) << 5));
            const u16x8 v = *(const u16x8*)(Cc + byte);
            *(u16x8*)(rwkv + ((size_t)(b * T_CTX + t0 + row_l)) * C_DIM + h * HS + k * 8) = v;
        }
        __syncthreads();
    }
}

// ---------------------------------------------------------------------------
extern "C" void kernel_launch(void* const* d_in, const int* in_sizes, int n_in,
                              void* d_out, int out_size, void* d_ws, size_t ws_size,
                              hipStream_t stream)
{
    const float* x     = (const float*)d_in[0];
    const float* tw    = (const float*)d_in[1];
    const float* alpha = (const float*)d_in[2];
    const float* beta  = (const float*)d_in[3];
    const float* gamma = (const float*)d_in[4];
    const float* Wk    = (const float*)d_in[5];
    const float* bk    = (const float*)d_in[6];
    const float* Wv    = (const float*)d_in[7];
    const float* bv    = (const float*)d_in[8];
    const float* Wr    = (const float*)d_in[9];
    const float* br    = (const float*)d_in[10];
    const float* Wo    = (const float*)d_in[11];
    const float* bo    = (const float*)d_in[12];
    float* out = (float*)d_out;

    // workspace layout (bytes), max 128M:
    //  [0,32M)   expk fp32    -> rwkv bf16 [0,16M) after cumsum
    //  [32,48M)  v bf16
    //  [48,56M)  weights bf16 (Wk,Wv,Wr,Wo stacked @ 2MB each)
    //  [56,56.5M) aux (raw 64-chunk totals)
    //  [64,96M)  sumk fp32 (chunk-local)  (xs bf16 overlays [64,80M) during proj)
    //  [96,112M) sigr bf16
    //  [112,128M) kvT bf16
    char* W = (char*)d_ws;
    float* expk          = (float*)W;
    unsigned short* rwkv = (unsigned short*)W;
    unsigned short* vbf  = (unsigned short*)(W + (32ull << 20));
    unsigned short* wbf  = (unsigned short*)(W + (48ull << 20));
    float* aux           = (float*)(W + (56ull << 20));
    float* sumk          = (float*)(W + (64ull << 20));
    unsigned short* xs   = (unsigned short*)(W + (64ull << 20));
    unsigned short* sigr = (unsigned short*)(W + (96ull << 20));
    unsigned short* kvT  = (unsigned short*)(W + (112ull << 20));

    const size_t WSZ = (size_t)C_DIM * C_DIM;

    convert_all<<<dim3(12288), 256, 0, stream>>>(x, xs, Wk, Wv, Wr, Wo, wbf);

    // k,v,r projections as one N=3072 GEMM (W stacked), XCD-swizzled
    mfma_gemm64<<<dim3(1536), 256, 0, stream>>>(
        xs, wbf, bk, bv, br, expk, vbf, sigr, gamma, 1);

    cumsum_chunk<<<dim3(4, 16, 8), 256, 0, stream>>>(expk, vbf, alpha, sumk, kvT, aux);

    // load-balanced pairs, XCD-clustered 1-D grid (512 blocks = 2/CU)
    wkv_mfma<<<dim3(512), 256, 0, stream>>>(
        kvT, sumk, sigr, tw, beta, aux, rwkv);

    // output projection + gamma
    mfma_gemm64<<<dim3(512), 256, 0, stream>>>(
        rwkv, wbf + 3 * WSZ, bo, nullptr, nullptr,
        out, nullptr, nullptr, gamma, 0);
}

// Round 10
// 248.845 us; speedup vs baseline: 1.0454x; 1.0454x over previous
//
#include <hip/hip_runtime.h>
#include <hip/hip_bf16.h>
#include <cstddef>
#include <cstdint>

#define B_SZ   8
#define T_CTX  1024
#define C_DIM  1024
#define H_NUM  16
#define HS     64
#define M_ROWS (B_SZ * T_CTX)

typedef __attribute__((ext_vector_type(8))) short bf16x8;
typedef __attribute__((ext_vector_type(8))) unsigned short u16x8;
typedef __attribute__((ext_vector_type(4))) float f32x4;

static __device__ inline unsigned short f2bf(float f) {
    __hip_bfloat16 h = __float2bfloat16(f);
    return __builtin_bit_cast(unsigned short, h);
}
static __device__ inline float bf2f(unsigned short u) {
    unsigned int v = ((unsigned int)u) << 16;
    return __builtin_bit_cast(float, v);
}
static __device__ inline void gld16(const void* g, void* l) {
    __builtin_amdgcn_global_load_lds((const __attribute__((address_space(1))) void*)g,
                                     (__attribute__((address_space(3))) void*)l,
                                     16, 0, 0);
}

// ---------------------------------------------------------------------------
// Fused conversion: blocks [0,8192) do x->xs (bf16, time-shifted);
// blocks [8192,12288) do the 4 weight matrices -> stacked bf16.
// ---------------------------------------------------------------------------
__global__ __launch_bounds__(256)
void convert_all(const float* __restrict__ x, unsigned short* __restrict__ xs,
                 const float* __restrict__ Wk, const float* __restrict__ Wv,
                 const float* __restrict__ Wr, const float* __restrict__ Wo,
                 unsigned short* __restrict__ wdst)
{
    const int bid = blockIdx.x;
    if (bid < 8192) {
        const int idx = (bid * 256 + threadIdx.x) * 4;
        const int m = idx >> 10;
        const int c = idx & 1023;
        float4 v;
        if (c < 512) {
            const int t = m & (T_CTX - 1);
            if (t == 0) v = make_float4(0.f, 0.f, 0.f, 0.f);
            else        v = *(const float4*)(x + (size_t)(m - 1) * C_DIM + c);
        } else {
            v = *(const float4*)(x + idx);
        }
        ushort4 o;
        o.x = f2bf(v.x); o.y = f2bf(v.y); o.z = f2bf(v.z); o.w = f2bf(v.w);
        *(ushort4*)(xs + idx) = o;
    } else {
        const int wid = bid - 8192;
        const int z = wid >> 10;
        const float* src = (z == 0) ? Wk : (z == 1) ? Wv : (z == 2) ? Wr : Wo;
        const int idx = ((wid & 1023) * 256 + threadIdx.x) * 4;
        const float4 v = *(const float4*)(src + idx);
        ushort4 o;
        o.x = f2bf(v.x); o.y = f2bf(v.y); o.z = f2bf(v.z); o.w = f2bf(v.w);
        *(ushort4*)(wdst + (size_t)z * (C_DIM * C_DIM) + idx) = o;
    }
}

// ---------------------------------------------------------------------------
// bf16 MFMA GEMM, BK=64, XOR-swizzled LDS (slot = chunk ^ (row&7)).
// FROZEN structure (r0-r8 proven): __launch_bounds__(256,2), 32 KiB LDS,
// 2-phase loop.  61 us / ~845 TF on the big GEMM.
// r10: ALL multi modes (0,1,2) now emit bf16 through the LDS-transposed
// epilogue (256B contiguous row stores, swizzle key ((row>>2)&7)<<5,
// conflict-free).  expk is bf16 now: halves mode-0 write (32->16MB) and
// cumsum's read; bf16 has fp32's exponent range so exp(clip) is safe.
// multi=1: W stacked [3072x1024]; mode = n0>>10:
//   0: exp(clip)->bf16 expk ; 1: identity->bf16 v ; 2: sigmoid->bf16 sigr
// multi=0: mode 3: (v+bias)*gamma[t] -> fp32 out (64B segments)
// Block swizzle: d -> y=((d&7)<<3)|((d>>3)&7), x=d>>6 (XCD L2 locality).
// ---------------------------------------------------------------------------
__global__ __launch_bounds__(256, 2)
void mfma_gemm64(const unsigned short* __restrict__ A,
                 const unsigned short* __restrict__ Wb,
                 const float* __restrict__ b0, const float* __restrict__ b1,
                 const float* __restrict__ b2,
                 void* __restrict__ o0, void* __restrict__ o1, void* __restrict__ o2,
                 const float* __restrict__ gamma, int multi)
{
    const int d  = blockIdx.x;
    const int y  = ((d & 7) << 3) | ((d >> 3) & 7);
    const int xb = d >> 6;
    const int m0 = y * 128, n0 = xb * 128;

    int mode, ncol0;
    const float* bias;
    void* out;
    if (multi) {
        const int z = n0 >> 10;
        mode = z;
        ncol0 = n0 & 1023;
        bias = (z == 0) ? b0 : (z == 1) ? b1 : b2;
        out  = (z == 0) ? o0 : (z == 1) ? o1 : o2;
    } else {
        mode = 3; ncol0 = n0; bias = b0; out = o0;
    }

    // single 32KB buffer: [0,8192) = A-tile, [8192,16384) = B-tile;
    // whole buffer reused as the bf16 C-staging area in the epilogue.
    __shared__ unsigned short Sh[2 * 128 * 64];

    const int tid = threadIdx.x;
    const int w = tid >> 6, l = tid & 63;

    const int r8  = l >> 3;
    const int c16 = ((l & 7) ^ r8) * 8;
    const unsigned short* gA = A  + (size_t)(m0 + w * 32 + r8) * C_DIM + c16;
    const unsigned short* gB = Wb + (size_t)(n0 + w * 32 + r8) * C_DIM + c16;
    char* lA = (char*)Sh + (w * 32) * 128;
    char* lB = (char*)Sh + 16384 + (w * 32) * 128;

    const int wr = w >> 1, wc = w & 1;
    const int lr = l & 15, lkq = l >> 4;
    const int x7 = lr & 7;

    f32x4 acc[4][4];
    #pragma unroll
    for (int i = 0; i < 4; ++i)
        #pragma unroll
        for (int j = 0; j < 4; ++j) acc[i][j] = (f32x4){0.f, 0.f, 0.f, 0.f};

    for (int k0 = 0; k0 < C_DIM; k0 += 64) {
        #pragma unroll
        for (int r = 0; r < 4; ++r) {
            gld16(gA + k0 + (size_t)r * 8 * C_DIM, lA + r * 8 * 128);
            gld16(gB + k0 + (size_t)r * 8 * C_DIM, lB + r * 8 * 128);
        }
        __syncthreads();

        bf16x8 af[2][4], bfv[2][4];
        #pragma unroll
        for (int ks = 0; ks < 2; ++ks) {
            const int slot = ((ks * 4 + lkq) ^ x7) * 8;   // swizzled k-offset
            #pragma unroll
            for (int i = 0; i < 4; ++i)
                af[ks][i] = *(const bf16x8*)&Sh[(wr * 64 + i * 16 + lr) * 64 + slot];
            #pragma unroll
            for (int j = 0; j < 4; ++j)
                bfv[ks][j] = *(const bf16x8*)&Sh[8192 + (wc * 64 + j * 16 + lr) * 64 + slot];
        }
        #pragma unroll
        for (int ks = 0; ks < 2; ++ks)
            #pragma unroll
            for (int i = 0; i < 4; ++i)
                #pragma unroll
                for (int j = 0; j < 4; ++j)
                    acc[i][j] = __builtin_amdgcn_mfma_f32_16x16x32_bf16(
                        af[ks][i], bfv[ks][j], acc[i][j], 0, 0, 0);
        __syncthreads();
    }

    // epilogue: C/D layout col=lane&15, row=(lane>>4)*4+reg
    if (multi) {
        // ---- all multi modes are bf16: LDS-transposed coalesced stores ----
        char* const Cs = (char*)Sh;   // 32KB, dead after final K-loop barrier
        #pragma unroll
        for (int j = 0; j < 4; ++j) {
            const int col_l = wc * 64 + j * 16 + lr;
            const float bz = bias[ncol0 + col_l];
            #pragma unroll
            for (int i = 0; i < 4; ++i) {
                const int rbl = wr * 64 + i * 16 + lkq * 4;
                #pragma unroll
                for (int r = 0; r < 4; ++r) {
                    const int row_l = rbl + r;
                    float v = acc[i][j][r] + bz;
                    if (mode == 0)      v = __expf(fminf(fmaxf(v, -60.f), 30.f));
                    else if (mode == 2) v = 1.f / (1.f + __expf(-v));
                    const int byte = row_l * 256 + ((col_l * 2) ^ (((row_l >> 2) & 7) << 5));
                    *(unsigned short*)(Cs + byte) = f2bf(v);
                }
            }
        }
        __syncthreads();
        // 16 lanes x 16B = 256B contiguous per output row; 8 rounds x 16 rows
        #pragma unroll
        for (int it = 0; it < 8; ++it) {
            const int row_l = (tid >> 4) + it * 16;
            const int k = tid & 15;
            const int byte = row_l * 256 + ((k * 16) ^ (((row_l >> 2) & 7) << 5));
            const u16x8 v = *(const u16x8*)(Cs + byte);
            *(u16x8*)((unsigned short*)out + (size_t)(m0 + row_l) * C_DIM + ncol0 + k * 8) = v;
        }
    } else {
        // ---- mode 3: fp32 out (64B segments, no amplification) ----
        #pragma unroll
        for (int j = 0; j < 4; ++j) {
            const int col = ncol0 + wc * 64 + j * 16 + lr;
            const float bz = bias[col];
            #pragma unroll
            for (int i = 0; i < 4; ++i) {
                const int rb = m0 + wr * 64 + i * 16 + lkq * 4;
                #pragma unroll
                for (int r = 0; r < 4; ++r) {
                    const int row = rb + r;
                    const float v = (acc[i][j][r] + bz) * gamma[row & (T_CTX - 1)];
                    ((float*)out)[(size_t)row * C_DIM + col] = v;
                }
            }
        }
    }
}

// ---------------------------------------------------------------------------
// Chunk-local cumsum of expk + kvT[b,h,c,u] = bf16(expk * v * alpha[h,u]).
// 64-row chunks (q in [0,16)); static u16x8 indexing (rule #20), 8-deep MLP.
// r10: expk is bf16 (halved read traffic; bf16 exponent range = fp32's, so
// the e^-60..e^30 values are representable; running sum s stays fp32).
// kvT stores transposed through LDS (r6 win): wave stages [64c][64u] tile
// (stride 68 -> <=4-way aliasing), writes 8x128B contiguous runs.
// sumk holds CHUNK-LOCAL prefix sums (fp32); aux[b,q,n] = raw chunk totals.
// ---------------------------------------------------------------------------
__global__ __launch_bounds__(256)
void cumsum_chunk(const unsigned short* __restrict__ expk, const unsigned short* __restrict__ vbf,
                  const float* __restrict__ alpha,
                  float* __restrict__ sumk, unsigned short* __restrict__ kvT,
                  float* __restrict__ aux)
{
    __shared__ unsigned short kvs[4][64 * 68];
    const int tid = threadIdx.x;
    const int w = tid >> 6, l = tid & 63;
    const int n = blockIdx.x * 256 + tid;    // channel; c = n&63 = l
    const int q = blockIdx.y;                // 16 chunks of 64 rows
    const int b = blockIdx.z;
    const int h = n >> 6;                    // = blockIdx.x*4 + w (wave-uniform)
    const size_t base = ((size_t)b * T_CTX + q * 64) * C_DIM + n;
    const float* arow = alpha + h * T_CTX + q * 64;

    float s = 0.f;
    for (int g = 0; g < 8; ++g) {
        u16x8 buf;
        #pragma unroll
        for (int k = 0; k < 8; ++k) {
            const int i = g * 8 + k;
            const size_t idx = base + (size_t)i * C_DIM;
            const float e  = bf2f(expk[idx]);
            const float vv = bf2f(vbf[idx]);
            s += e;
            sumk[idx] = s;
            buf[k] = f2bf(e * vv * arow[i]);
        }
        *(u16x8*)&kvs[w][l * 68 + g * 8] = buf;
    }
    aux[((size_t)b * 16 + q) * C_DIM + n] = s;

    __syncthreads();

    // transposed write-out: lane l covers row c2=(l>>3)+r*8, u-slice (l&7)*8.
    const int u8 = (l & 7) * 8;
    #pragma unroll
    for (int r = 0; r < 8; ++r) {
        const int c2 = (l >> 3) + r * 8;
        const u16x8 v = *(const u16x8*)&kvs[w][c2 * 68 + u8];
        *(u16x8*)(kvT + (((size_t)b * H_NUM + h) * HS + c2) * T_CTX + q * 64 + u8) = v;
    }
}

// ---------------------------------------------------------------------------
// wkv via MFMA (Toeplitz):  wkv[t,c] = sum_u twx[1023-t+u] * kvT[c,u]
// R8-PROVEN VERSION (r9's XCD-cluster/dbuf/hoist package was session-
// normalized neutral -> reverted).  Load-balanced chunk pairing (bxp, 7-bxp)
// -> constant 18 steps/block.  Epilogue staged in dedicated cst (16KB),
// swizzle key ((row>>2)&3)<<5 -> conflict-free 128B runs.
// ---------------------------------------------------------------------------
#define REPL_STRIDE 1176
#define REPL_USED   1168

__global__ __launch_bounds__(256)
void wkv_mfma(const unsigned short* __restrict__ kvT,
              const float* __restrict__ sumk,
              const unsigned short* __restrict__ sigr,
              const float* __restrict__ tw, const float* __restrict__ beta,
              const float* __restrict__ aux,
              unsigned short* __restrict__ rwkv)
{
    __shared__ unsigned short repl[8 * REPL_STRIDE];
    __shared__ unsigned short kv_s[64 * 72];
    __shared__ unsigned short tw_s[1024];
    __shared__ unsigned short cst[128 * 64];   // epilogue staging (16KB)

    const int tid = threadIdx.x;
    const int bxp = blockIdx.x;              // 0..3 -> pair (bxp, 7-bxp)
    const int h  = blockIdx.y;
    const int b  = blockIdx.z;

    {
        const int i = tid * 4;
        const float4 v = *(const float4*)(tw + h * T_CTX + i);
        ushort4 o;
        o.x = f2bf(v.x); o.y = f2bf(v.y); o.z = f2bf(v.z); o.w = f2bf(v.w);
        *(ushort4*)&tw_s[i] = o;
    }
    __syncthreads();

    #pragma unroll
    for (int r = 0; r < 8; ++r)
        for (int i = tid; i < REPL_USED; i += 256) {
            const int src = i + r;
            repl[r * REPL_STRIDE + i] = (src < 1024) ? tw_s[src] : (unsigned short)0;
        }

    const int w = tid >> 6, l = tid & 63;
    const int wr = w >> 1, wc = w & 1;
    const int lr = l & 15, lkq = l >> 4;
    const int r    = (7 - lr) & 7;
    const char* repl_c = (const char*)repl;

    const int srow = tid >> 2;
    const int ucol = (tid & 3) * 16;
    const unsigned short* gkv = kvT + (((size_t)b * H_NUM + h) * HS + srow) * T_CTX + ucol;
    unsigned short* skv = &kv_s[srow * 72 + ucol];

    for (int pass = 0; pass < 2; ++pass) {
        const int bx = pass ? (7 - bxp) : bxp;
        const int t0 = bx * 128;
        const int S0 = 1023 - t0 - wr * 64 - lr + lkq * 8;
        const int abase = 2 * S0 + (2 * REPL_STRIDE - 2) * r;

        f32x4 acc[4][2];
        #pragma unroll
        for (int i = 0; i < 4; ++i) {
            acc[i][0] = (f32x4){0.f, 0.f, 0.f, 0.f};
            acc[i][1] = (f32x4){0.f, 0.f, 0.f, 0.f};
        }

        const int nsteps = t0 / 64 + 2;
        u16x8 q0 = *(const u16x8*)(gkv);
        u16x8 q1 = *(const u16x8*)(gkv + 8);
        for (int ks = 0; ks < nsteps; ++ks) {
            __syncthreads();
            *(u16x8*)skv       = q0;
            *(u16x8*)(skv + 8) = q1;
            __syncthreads();
            if (ks + 1 < nsteps) {
                const int un = (ks + 1) * 64;
                q0 = *(const u16x8*)(gkv + un);
                q1 = *(const u16x8*)(gkv + un + 8);
            }

            const int ub = abase + 2 * (ks * 64);
            #pragma unroll
            for (int kk = 0; kk < 2; ++kk) {
                bf16x8 af[4], bfv[2];
                #pragma unroll
                for (int i = 0; i < 4; ++i)
                    af[i] = *(const bf16x8*)(repl_c + (ub + kk * 64 - i * 32));
                #pragma unroll
                for (int j = 0; j < 2; ++j)
                    bfv[j] = *(const bf16x8*)&kv_s[(wc * 32 + j * 16 + lr) * 72 + kk * 32 + lkq * 8];
                #pragma unroll
                for (int i = 0; i < 4; ++i)
                    #pragma unroll
                    for (int j = 0; j < 2; ++j)
                        acc[i][j] = __builtin_amdgcn_mfma_f32_16x16x32_bf16(
                            af[i], bfv[j], acc[i][j], 0, 0, 0);
            }
        }

        // aux prefix: this thread's rows live in 64-chunk (2*bx + wr)
        const int cq = 2 * bx + wr;
        float off[2];
        #pragma unroll
        for (int j = 0; j < 2; ++j) {
            const int cl = wc * 32 + j * 16 + lr;
            float o = 0.f;
            for (int q = 0; q < cq; ++q)
                o += aux[((size_t)b * 16 + q) * C_DIM + h * HS + cl];
            off[j] = o;
        }

        // ---- epilogue via dedicated cst staging ----
        char* const Cc = (char*)cst;   // 128 rows x 64 ch bf16 = 16KB
        #pragma unroll
        for (int i = 0; i < 4; ++i) {
            const int rbl = wr * 64 + i * 16 + lkq * 4;
            #pragma unroll
            for (int rg = 0; rg < 4; ++rg) {
                const int row_l = rbl + rg;
                const int t = t0 + row_l;
                const float bet = beta[h * T_CTX + t];
                const size_t row_off = ((size_t)(b * T_CTX + t)) * C_DIM + h * HS;
                #pragma unroll
                for (int j = 0; j < 2; ++j) {
                    const int cl = wc * 32 + j * 16 + lr;
                    const float sk = sumk[row_off + cl] + off[j];
                    const float sr = bf2f(sigr[row_off + cl]);
                    const int byte = row_l * 128 + ((cl * 2) ^ (((row_l >> 2) & 3) << 5));
                    *(unsigned short*)(Cc + byte) = f2bf(sr * bet * acc[i][j][rg] / sk);
                }
            }
        }
        __syncthreads();
        // 8 lanes x 16B = 128B contiguous per row; 4 rounds x 32 rows
        #pragma unroll
        for (int it = 0; it < 4; ++it) {
            const int row_l = (tid >> 3) + it * 32;
            const int k = tid & 7;
            const int byte = row_l * 128 + ((k * 16) ^ (((row_l >> 2) & 3) << 5));
            const u16x8 v = *(const u16x8*)(Cc + byte);
            *(u16x8*)(rwkv + ((size_t)(b * T_CTX + t0 + row_l)) * C_DIM + h * HS + k * 8) = v;
        }
        __syncthreads();
    }
}

// ---------------------------------------------------------------------------
extern "C" void kernel_launch(void* const* d_in, const int* in_sizes, int n_in,
                              void* d_out, int out_size, void* d_ws, size_t ws_size,
                              hipStream_t stream)
{
    const float* x     = (const float*)d_in[0];
    const float* tw    = (const float*)d_in[1];
    const float* alpha = (const float*)d_in[2];
    const float* beta  = (const float*)d_in[3];
    const float* gamma = (const float*)d_in[4];
    const float* Wk    = (const float*)d_in[5];
    const float* bk    = (const float*)d_in[6];
    const float* Wv    = (const float*)d_in[7];
    const float* bv    = (const float*)d_in[8];
    const float* Wr    = (const float*)d_in[9];
    const float* br    = (const float*)d_in[10];
    const float* Wo    = (const float*)d_in[11];
    const float* bo    = (const float*)d_in[12];
    float* out = (float*)d_out;

    // workspace layout (bytes), max 128M:
    //  [0,16M)   rwkv bf16 (wkv output)
    //  [16,32M)  expk bf16 (r10: was fp32 32MB)
    //  [32,48M)  v bf16
    //  [48,56M)  weights bf16 (Wk,Wv,Wr,Wo stacked @ 2MB each)
    //  [56,56.5M) aux (raw 64-chunk totals)
    //  [64,96M)  sumk fp32 (chunk-local)  (xs bf16 overlays [64,80M) during proj)
    //  [96,112M) sigr bf16
    //  [112,128M) kvT bf16
    char* W = (char*)d_ws;
    unsigned short* rwkv = (unsigned short*)W;
    unsigned short* expk = (unsigned short*)(W + (16ull << 20));
    unsigned short* vbf  = (unsigned short*)(W + (32ull << 20));
    unsigned short* wbf  = (unsigned short*)(W + (48ull << 20));
    float* aux           = (float*)(W + (56ull << 20));
    float* sumk          = (float*)(W + (64ull << 20));
    unsigned short* xs   = (unsigned short*)(W + (64ull << 20));
    unsigned short* sigr = (unsigned short*)(W + (96ull << 20));
    unsigned short* kvT  = (unsigned short*)(W + (112ull << 20));

    const size_t WSZ = (size_t)C_DIM * C_DIM;

    convert_all<<<dim3(12288), 256, 0, stream>>>(x, xs, Wk, Wv, Wr, Wo, wbf);

    // k,v,r projections as one N=3072 GEMM (W stacked), XCD-swizzled
    mfma_gemm64<<<dim3(1536), 256, 0, stream>>>(
        xs, wbf, bk, bv, br, expk, vbf, sigr, gamma, 1);

    cumsum_chunk<<<dim3(4, 16, 8), 256, 0, stream>>>(expk, vbf, alpha, sumk, kvT, aux);

    // load-balanced: each block does chunk pair (bx, 7-bx) = constant 18 steps
    wkv_mfma<<<dim3(4, 16, 8), 256, 0, stream>>>(
        kvT, sumk, sigr, tw, beta, aux, rwkv);

    // output projection + gamma
    mfma_gemm64<<<dim3(512), 256, 0, stream>>>(
        rwkv, wbf + 3 * WSZ, bo, nullptr, nullptr,
        out, nullptr, nullptr, gamma, 0);
}

// Round 11
// 235.693 us; speedup vs baseline: 1.1038x; 1.0558x over previous
//
#include <hip/hip_runtime.h>
#include <hip/hip_bf16.h>
#include <cstddef>
#include <cstdint>

#define B_SZ   8
#define T_CTX  1024
#define C_DIM  1024
#define H_NUM  16
#define HS     64
#define M_ROWS (B_SZ * T_CTX)

typedef __attribute__((ext_vector_type(8))) short bf16x8;
typedef __attribute__((ext_vector_type(8))) unsigned short u16x8;
typedef __attribute__((ext_vector_type(4))) float f32x4;

static __device__ inline unsigned short f2bf(float f) {
    __hip_bfloat16 h = __float2bfloat16(f);
    return __builtin_bit_cast(unsigned short, h);
}
static __device__ inline float bf2f(unsigned short u) {
    unsigned int v = ((unsigned int)u) << 16;
    return __builtin_bit_cast(float, v);
}
static __device__ inline void gld16(const void* g, void* l) {
    __builtin_amdgcn_global_load_lds((const __attribute__((address_space(1))) void*)g,
                                     (__attribute__((address_space(3))) void*)l,
                                     16, 0, 0);
}

// ---------------------------------------------------------------------------
// Fused conversion: blocks [0,8192) do x->xs (bf16, time-shifted);
// blocks [8192,12288) do the 4 weight matrices -> stacked bf16.
// ---------------------------------------------------------------------------
__global__ __launch_bounds__(256)
void convert_all(const float* __restrict__ x, unsigned short* __restrict__ xs,
                 const float* __restrict__ Wk, const float* __restrict__ Wv,
                 const float* __restrict__ Wr, const float* __restrict__ Wo,
                 unsigned short* __restrict__ wdst)
{
    const int bid = blockIdx.x;
    if (bid < 8192) {
        const int idx = (bid * 256 + threadIdx.x) * 4;
        const int m = idx >> 10;
        const int c = idx & 1023;
        float4 v;
        if (c < 512) {
            const int t = m & (T_CTX - 1);
            if (t == 0) v = make_float4(0.f, 0.f, 0.f, 0.f);
            else        v = *(const float4*)(x + (size_t)(m - 1) * C_DIM + c);
        } else {
            v = *(const float4*)(x + idx);
        }
        ushort4 o;
        o.x = f2bf(v.x); o.y = f2bf(v.y); o.z = f2bf(v.z); o.w = f2bf(v.w);
        *(ushort4*)(xs + idx) = o;
    } else {
        const int wid = bid - 8192;
        const int z = wid >> 10;
        const float* src = (z == 0) ? Wk : (z == 1) ? Wv : (z == 2) ? Wr : Wo;
        const int idx = ((wid & 1023) * 256 + threadIdx.x) * 4;
        const float4 v = *(const float4*)(src + idx);
        ushort4 o;
        o.x = f2bf(v.x); o.y = f2bf(v.y); o.z = f2bf(v.z); o.w = f2bf(v.w);
        *(ushort4*)(wdst + (size_t)z * (C_DIM * C_DIM) + idx) = o;
    }
}

// ---------------------------------------------------------------------------
// bf16 MFMA GEMM, BK=64, XOR-swizzled LDS (slot = chunk ^ (row&7)).
// FROZEN structure (r0-r8 proven): __launch_bounds__(256,2), 32 KiB LDS,
// 2-phase loop.  ~61 us / ~845 TF on the big GEMM (healthy session).
// r10: ALL multi modes (0,1,2) emit bf16 through the LDS-transposed
// epilogue (256B contiguous rows, swizzle key ((row>>2)&7)<<5, 0 conflicts);
// WRITE_SIZE 79 -> 48MB confirmed by counters.
// multi=1: W stacked [3072x1024]; mode = n0>>10:
//   0: exp(clip)->bf16 expk ; 1: identity->bf16 v ; 2: sigmoid->bf16 sigr
// multi=0: mode 3: (v+bias)*gamma[t] -> fp32 out (64B segments)
// Block swizzle: d -> y=((d&7)<<3)|((d>>3)&7), x=d>>6 (XCD L2 locality).
// ---------------------------------------------------------------------------
__global__ __launch_bounds__(256, 2)
void mfma_gemm64(const unsigned short* __restrict__ A,
                 const unsigned short* __restrict__ Wb,
                 const float* __restrict__ b0, const float* __restrict__ b1,
                 const float* __restrict__ b2,
                 void* __restrict__ o0, void* __restrict__ o1, void* __restrict__ o2,
                 const float* __restrict__ gamma, int multi)
{
    const int d  = blockIdx.x;
    const int y  = ((d & 7) << 3) | ((d >> 3) & 7);
    const int xb = d >> 6;
    const int m0 = y * 128, n0 = xb * 128;

    int mode, ncol0;
    const float* bias;
    void* out;
    if (multi) {
        const int z = n0 >> 10;
        mode = z;
        ncol0 = n0 & 1023;
        bias = (z == 0) ? b0 : (z == 1) ? b1 : b2;
        out  = (z == 0) ? o0 : (z == 1) ? o1 : o2;
    } else {
        mode = 3; ncol0 = n0; bias = b0; out = o0;
    }

    // single 32KB buffer: [0,8192) = A-tile, [8192,16384) = B-tile;
    // whole buffer reused as the bf16 C-staging area in the epilogue.
    __shared__ unsigned short Sh[2 * 128 * 64];

    const int tid = threadIdx.x;
    const int w = tid >> 6, l = tid & 63;

    const int r8  = l >> 3;
    const int c16 = ((l & 7) ^ r8) * 8;
    const unsigned short* gA = A  + (size_t)(m0 + w * 32 + r8) * C_DIM + c16;
    const unsigned short* gB = Wb + (size_t)(n0 + w * 32 + r8) * C_DIM + c16;
    char* lA = (char*)Sh + (w * 32) * 128;
    char* lB = (char*)Sh + 16384 + (w * 32) * 128;

    const int wr = w >> 1, wc = w & 1;
    const int lr = l & 15, lkq = l >> 4;
    const int x7 = lr & 7;

    f32x4 acc[4][4];
    #pragma unroll
    for (int i = 0; i < 4; ++i)
        #pragma unroll
        for (int j = 0; j < 4; ++j) acc[i][j] = (f32x4){0.f, 0.f, 0.f, 0.f};

    for (int k0 = 0; k0 < C_DIM; k0 += 64) {
        #pragma unroll
        for (int r = 0; r < 4; ++r) {
            gld16(gA + k0 + (size_t)r * 8 * C_DIM, lA + r * 8 * 128);
            gld16(gB + k0 + (size_t)r * 8 * C_DIM, lB + r * 8 * 128);
        }
        __syncthreads();

        bf16x8 af[2][4], bfv[2][4];
        #pragma unroll
        for (int ks = 0; ks < 2; ++ks) {
            const int slot = ((ks * 4 + lkq) ^ x7) * 8;   // swizzled k-offset
            #pragma unroll
            for (int i = 0; i < 4; ++i)
                af[ks][i] = *(const bf16x8*)&Sh[(wr * 64 + i * 16 + lr) * 64 + slot];
            #pragma unroll
            for (int j = 0; j < 4; ++j)
                bfv[ks][j] = *(const bf16x8*)&Sh[8192 + (wc * 64 + j * 16 + lr) * 64 + slot];
        }
        #pragma unroll
        for (int ks = 0; ks < 2; ++ks)
            #pragma unroll
            for (int i = 0; i < 4; ++i)
                #pragma unroll
                for (int j = 0; j < 4; ++j)
                    acc[i][j] = __builtin_amdgcn_mfma_f32_16x16x32_bf16(
                        af[ks][i], bfv[ks][j], acc[i][j], 0, 0, 0);
        __syncthreads();
    }

    // epilogue: C/D layout col=lane&15, row=(lane>>4)*4+reg
    if (multi) {
        // ---- all multi modes are bf16: LDS-transposed coalesced stores ----
        char* const Cs = (char*)Sh;   // 32KB, dead after final K-loop barrier
        #pragma unroll
        for (int j = 0; j < 4; ++j) {
            const int col_l = wc * 64 + j * 16 + lr;
            const float bz = bias[ncol0 + col_l];
            #pragma unroll
            for (int i = 0; i < 4; ++i) {
                const int rbl = wr * 64 + i * 16 + lkq * 4;
                #pragma unroll
                for (int r = 0; r < 4; ++r) {
                    const int row_l = rbl + r;
                    float v = acc[i][j][r] + bz;
                    if (mode == 0)      v = __expf(fminf(fmaxf(v, -60.f), 30.f));
                    else if (mode == 2) v = 1.f / (1.f + __expf(-v));
                    const int byte = row_l * 256 + ((col_l * 2) ^ (((row_l >> 2) & 7) << 5));
                    *(unsigned short*)(Cs + byte) = f2bf(v);
                }
            }
        }
        __syncthreads();
        // 16 lanes x 16B = 256B contiguous per output row; 8 rounds x 16 rows
        #pragma unroll
        for (int it = 0; it < 8; ++it) {
            const int row_l = (tid >> 4) + it * 16;
            const int k = tid & 15;
            const int byte = row_l * 256 + ((k * 16) ^ (((row_l >> 2) & 7) << 5));
            const u16x8 v = *(const u16x8*)(Cs + byte);
            *(u16x8*)((unsigned short*)out + (size_t)(m0 + row_l) * C_DIM + ncol0 + k * 8) = v;
        }
    } else {
        // ---- mode 3: fp32 out (64B segments, no amplification) ----
        #pragma unroll
        for (int j = 0; j < 4; ++j) {
            const int col = ncol0 + wc * 64 + j * 16 + lr;
            const float bz = bias[col];
            #pragma unroll
            for (int i = 0; i < 4; ++i) {
                const int rb = m0 + wr * 64 + i * 16 + lkq * 4;
                #pragma unroll
                for (int r = 0; r < 4; ++r) {
                    const int row = rb + r;
                    const float v = (acc[i][j][r] + bz) * gamma[row & (T_CTX - 1)];
                    ((float*)out)[(size_t)row * C_DIM + col] = v;
                }
            }
        }
    }
}

// ---------------------------------------------------------------------------
// Chunk-local cumsum of expk + kvT[b,h,c,u] = bf16(expk * v * alpha[h,u]).
// 64-row chunks (q in [0,16)); static u16x8 indexing (rule #20), 8-deep MLP.
// r10: expk bf16.  r11: sumk stored as BF16 (was fp32) — halves the largest
// remaining traffic item (32MB write + 32MB read in wkv -> 16+16).  Running
// sum s stays fp32; only the stored chunk-local prefix is rounded (<=0.2%
// rel err on the divisor's chunk-local part; aux addend stays fp32).
// kvT stores transposed through LDS (r6 win): wave stages [64c][64u] tile
// (stride 68 -> <=4-way aliasing), writes 8x128B contiguous runs.
// ---------------------------------------------------------------------------
__global__ __launch_bounds__(256)
void cumsum_chunk(const unsigned short* __restrict__ expk, const unsigned short* __restrict__ vbf,
                  const float* __restrict__ alpha,
                  unsigned short* __restrict__ sumk, unsigned short* __restrict__ kvT,
                  float* __restrict__ aux)
{
    __shared__ unsigned short kvs[4][64 * 68];
    const int tid = threadIdx.x;
    const int w = tid >> 6, l = tid & 63;
    const int n = blockIdx.x * 256 + tid;    // channel; c = n&63 = l
    const int q = blockIdx.y;                // 16 chunks of 64 rows
    const int b = blockIdx.z;
    const int h = n >> 6;                    // = blockIdx.x*4 + w (wave-uniform)
    const size_t base = ((size_t)b * T_CTX + q * 64) * C_DIM + n;
    const float* arow = alpha + h * T_CTX + q * 64;

    float s = 0.f;
    for (int g = 0; g < 8; ++g) {
        u16x8 buf;
        #pragma unroll
        for (int k = 0; k < 8; ++k) {
            const int i = g * 8 + k;
            const size_t idx = base + (size_t)i * C_DIM;
            const float e  = bf2f(expk[idx]);
            const float vv = bf2f(vbf[idx]);
            s += e;
            sumk[idx] = f2bf(s);
            buf[k] = f2bf(e * vv * arow[i]);
        }
        *(u16x8*)&kvs[w][l * 68 + g * 8] = buf;
    }
    aux[((size_t)b * 16 + q) * C_DIM + n] = s;

    __syncthreads();

    // transposed write-out: lane l covers row c2=(l>>3)+r*8, u-slice (l&7)*8.
    const int u8 = (l & 7) * 8;
    #pragma unroll
    for (int r = 0; r < 8; ++r) {
        const int c2 = (l >> 3) + r * 8;
        const u16x8 v = *(const u16x8*)&kvs[w][c2 * 68 + u8];
        *(u16x8*)(kvT + (((size_t)b * H_NUM + h) * HS + c2) * T_CTX + q * 64 + u8) = v;
    }
}

// ---------------------------------------------------------------------------
// wkv via MFMA (Toeplitz):  wkv[t,c] = sum_u twx[1023-t+u] * kvT[c,u]
// R8-PROVEN structure.  Load-balanced chunk pairing (bxp, 7-bxp) ->
// constant 18 steps/block.  Epilogue staged in dedicated cst (16KB),
// swizzle key ((row>>2)&3)<<5 -> conflict-free 128B runs.
// r11: sumk read as bf16 (chunk-local part); aux prefix added in fp32.
// ---------------------------------------------------------------------------
#define REPL_STRIDE 1176
#define REPL_USED   1168

__global__ __launch_bounds__(256)
void wkv_mfma(const unsigned short* __restrict__ kvT,
              const unsigned short* __restrict__ sumk,
              const unsigned short* __restrict__ sigr,
              const float* __restrict__ tw, const float* __restrict__ beta,
              const float* __restrict__ aux,
              unsigned short* __restrict__ rwkv)
{
    __shared__ unsigned short repl[8 * REPL_STRIDE];
    __shared__ unsigned short kv_s[64 * 72];
    __shared__ unsigned short tw_s[1024];
    __shared__ unsigned short cst[128 * 64];   // epilogue staging (16KB)

    const int tid = threadIdx.x;
    const int bxp = blockIdx.x;              // 0..3 -> pair (bxp, 7-bxp)
    const int h  = blockIdx.y;
    const int b  = blockIdx.z;

    {
        const int i = tid * 4;
        const float4 v = *(const float4*)(tw + h * T_CTX + i);
        ushort4 o;
        o.x = f2bf(v.x); o.y = f2bf(v.y); o.z = f2bf(v.z); o.w = f2bf(v.w);
        *(ushort4*)&tw_s[i] = o;
    }
    __syncthreads();

    #pragma unroll
    for (int r = 0; r < 8; ++r)
        for (int i = tid; i < REPL_USED; i += 256) {
            const int src = i + r;
            repl[r * REPL_STRIDE + i] = (src < 1024) ? tw_s[src] : (unsigned short)0;
        }

    const int w = tid >> 6, l = tid & 63;
    const int wr = w >> 1, wc = w & 1;
    const int lr = l & 15, lkq = l >> 4;
    const int r    = (7 - lr) & 7;
    const char* repl_c = (const char*)repl;

    const int srow = tid >> 2;
    const int ucol = (tid & 3) * 16;
    const unsigned short* gkv = kvT + (((size_t)b * H_NUM + h) * HS + srow) * T_CTX + ucol;
    unsigned short* skv = &kv_s[srow * 72 + ucol];

    for (int pass = 0; pass < 2; ++pass) {
        const int bx = pass ? (7 - bxp) : bxp;
        const int t0 = bx * 128;
        const int S0 = 1023 - t0 - wr * 64 - lr + lkq * 8;
        const int abase = 2 * S0 + (2 * REPL_STRIDE - 2) * r;

        f32x4 acc[4][2];
        #pragma unroll
        for (int i = 0; i < 4; ++i) {
            acc[i][0] = (f32x4){0.f, 0.f, 0.f, 0.f};
            acc[i][1] = (f32x4){0.f, 0.f, 0.f, 0.f};
        }

        const int nsteps = t0 / 64 + 2;
        u16x8 q0 = *(const u16x8*)(gkv);
        u16x8 q1 = *(const u16x8*)(gkv + 8);
        for (int ks = 0; ks < nsteps; ++ks) {
            __syncthreads();
            *(u16x8*)skv       = q0;
            *(u16x8*)(skv + 8) = q1;
            __syncthreads();
            if (ks + 1 < nsteps) {
                const int un = (ks + 1) * 64;
                q0 = *(const u16x8*)(gkv + un);
                q1 = *(const u16x8*)(gkv + un + 8);
            }

            const int ub = abase + 2 * (ks * 64);
            #pragma unroll
            for (int kk = 0; kk < 2; ++kk) {
                bf16x8 af[4], bfv[2];
                #pragma unroll
                for (int i = 0; i < 4; ++i)
                    af[i] = *(const bf16x8*)(repl_c + (ub + kk * 64 - i * 32));
                #pragma unroll
                for (int j = 0; j < 2; ++j)
                    bfv[j] = *(const bf16x8*)&kv_s[(wc * 32 + j * 16 + lr) * 72 + kk * 32 + lkq * 8];
                #pragma unroll
                for (int i = 0; i < 4; ++i)
                    #pragma unroll
                    for (int j = 0; j < 2; ++j)
                        acc[i][j] = __builtin_amdgcn_mfma_f32_16x16x32_bf16(
                            af[i], bfv[j], acc[i][j], 0, 0, 0);
            }
        }

        // aux prefix: this thread's rows live in 64-chunk (2*bx + wr)
        const int cq = 2 * bx + wr;
        float off[2];
        #pragma unroll
        for (int j = 0; j < 2; ++j) {
            const int cl = wc * 32 + j * 16 + lr;
            float o = 0.f;
            for (int q = 0; q < cq; ++q)
                o += aux[((size_t)b * 16 + q) * C_DIM + h * HS + cl];
            off[j] = o;
        }

        // ---- epilogue via dedicated cst staging ----
        char* const Cc = (char*)cst;   // 128 rows x 64 ch bf16 = 16KB
        #pragma unroll
        for (int i = 0; i < 4; ++i) {
            const int rbl = wr * 64 + i * 16 + lkq * 4;
            #pragma unroll
            for (int rg = 0; rg < 4; ++rg) {
                const int row_l = rbl + rg;
                const int t = t0 + row_l;
                const float bet = beta[h * T_CTX + t];
                const size_t row_off = ((size_t)(b * T_CTX + t)) * C_DIM + h * HS;
                #pragma unroll
                for (int j = 0; j < 2; ++j) {
                    const int cl = wc * 32 + j * 16 + lr;
                    const float sk = bf2f(sumk[row_off + cl]) + off[j];
                    const float sr = bf2f(sigr[row_off + cl]);
                    const int byte = row_l * 128 + ((cl * 2) ^ (((row_l >> 2) & 3) << 5));
                    *(unsigned short*)(Cc + byte) = f2bf(sr * bet * acc[i][j][rg] / sk);
                }
            }
        }
        __syncthreads();
        // 8 lanes x 16B = 128B contiguous per row; 4 rounds x 32 rows
        #pragma unroll
        for (int it = 0; it < 4; ++it) {
            const int row_l = (tid >> 3) + it * 32;
            const int k = tid & 7;
            const int byte = row_l * 128 + ((k * 16) ^ (((row_l >> 2) & 3) << 5));
            const u16x8 v = *(const u16x8*)(Cc + byte);
            *(u16x8*)(rwkv + ((size_t)(b * T_CTX + t0 + row_l)) * C_DIM + h * HS + k * 8) = v;
        }
        __syncthreads();
    }
}

// ---------------------------------------------------------------------------
extern "C" void kernel_launch(void* const* d_in, const int* in_sizes, int n_in,
                              void* d_out, int out_size, void* d_ws, size_t ws_size,
                              hipStream_t stream)
{
    const float* x     = (const float*)d_in[0];
    const float* tw    = (const float*)d_in[1];
    const float* alpha = (const float*)d_in[2];
    const float* beta  = (const float*)d_in[3];
    const float* gamma = (const float*)d_in[4];
    const float* Wk    = (const float*)d_in[5];
    const float* bk    = (const float*)d_in[6];
    const float* Wv    = (const float*)d_in[7];
    const float* bv    = (const float*)d_in[8];
    const float* Wr    = (const float*)d_in[9];
    const float* br    = (const float*)d_in[10];
    const float* Wo    = (const float*)d_in[11];
    const float* bo    = (const float*)d_in[12];
    float* out = (float*)d_out;

    // workspace layout (bytes), max 128M:
    //  [0,16M)   rwkv bf16 (wkv output)
    //  [16,32M)  expk bf16
    //  [32,48M)  v bf16
    //  [48,56M)  weights bf16 (Wk,Wv,Wr,Wo stacked @ 2MB each)
    //  [56,56.5M) aux (raw 64-chunk totals, fp32)
    //  [64,80M)  sumk bf16 (r11: was fp32 32MB)  (xs bf16 overlays during proj)
    //  [96,112M) sigr bf16
    //  [112,128M) kvT bf16
    char* W = (char*)d_ws;
    unsigned short* rwkv = (unsigned short*)W;
    unsigned short* expk = (unsigned short*)(W + (16ull << 20));
    unsigned short* vbf  = (unsigned short*)(W + (32ull << 20));
    unsigned short* wbf  = (unsigned short*)(W + (48ull << 20));
    float* aux           = (float*)(W + (56ull << 20));
    unsigned short* sumk = (unsigned short*)(W + (64ull << 20));
    unsigned short* xs   = (unsigned short*)(W + (64ull << 20));
    unsigned short* sigr = (unsigned short*)(W + (96ull << 20));
    unsigned short* kvT  = (unsigned short*)(W + (112ull << 20));

    const size_t WSZ = (size_t)C_DIM * C_DIM;

    convert_all<<<dim3(12288), 256, 0, stream>>>(x, xs, Wk, Wv, Wr, Wo, wbf);

    // k,v,r projections as one N=3072 GEMM (W stacked), XCD-swizzled
    mfma_gemm64<<<dim3(1536), 256, 0, stream>>>(
        xs, wbf, bk, bv, br, expk, vbf, sigr, gamma, 1);

    cumsum_chunk<<<dim3(4, 16, 8), 256, 0, stream>>>(expk, vbf, alpha, sumk, kvT, aux);

    // load-balanced: each block does chunk pair (bx, 7-bx) = constant 18 steps
    wkv_mfma<<<dim3(4, 16, 8), 256, 0, stream>>>(
        kvT, sumk, sigr, tw, beta, aux, rwkv);

    // output projection + gamma
    mfma_gemm64<<<dim3(512), 256, 0, stream>>>(
        rwkv, wbf + 3 * WSZ, bo, nullptr, nullptr,
        out, nullptr, nullptr, gamma, 0);
}